// Round 10
// baseline (525.952 us; speedup 1.0000x reference)
//
#include <hip/hip_runtime.h>

#define N_NODES 50000
#define N_EDGES 800000
#define N_GRAPHS 256
#define DIN 126
#define H 128
#define MP 50048           // N_NODES padded to 128
#define NB_SCAN 196        // ceil(N_NODES/256)

typedef __attribute__((ext_vector_type(8))) short short8v;
typedef __attribute__((ext_vector_type(8))) _Float16 half8v;
typedef __attribute__((ext_vector_type(4))) float f32x4;

// ---------------------------------------------------------------------------
// fp32 -> bf16 hi/lo split helpers (RNE)
// ---------------------------------------------------------------------------
__device__ __forceinline__ unsigned short f2bf(float f) {
    const unsigned u = __float_as_uint(f);
    return (unsigned short)((u + 0x7FFFu + ((u >> 16) & 1u)) >> 16);
}
__device__ __forceinline__ float bf2f(unsigned short s) {
    return __uint_as_float(((unsigned)s) << 16);
}

// ---------------------------------------------------------------------------
// A conversion (layer-1 input only): X fp32 [M,Kd] -> Ah,Al bf16 [MP][128]
// ---------------------------------------------------------------------------
__global__ __launch_bounds__(256) void conv_A(const float* __restrict__ X, int M, int Kd,
                                              short* __restrict__ Ah,
                                              short* __restrict__ Al)
{
    const int t = blockIdx.x * 256 + threadIdx.x;
    const int row = t >> 4;
    if (row >= MP) return;
    const int k0 = (t & 15) * 8;
    short8v hv, lv;
    #pragma unroll
    for (int j = 0; j < 8; ++j) {
        const int k = k0 + j;
        float v = 0.f;
        if (row < M && k < Kd) v = X[(size_t)row * Kd + k];
        const unsigned short hb = f2bf(v);
        const float lo = v - bf2f(hb);
        hv[j] = (short)hb;
        lv[j] = (short)f2bf(lo);
    }
    const size_t o = (size_t)row * 128 + k0;
    *(short8v*)&Ah[o] = hv;
    *(short8v*)&Al[o] = lv;
}

// ---------------------------------------------------------------------------
// W conversion (one layer): four [Kd,128] fp32 -> transposed Wth/Wtl bf16
// ---------------------------------------------------------------------------
__global__ __launch_bounds__(256) void conv_W(
    const float* __restrict__ W0, const float* __restrict__ W1,
    const float* __restrict__ W2, const float* __restrict__ W3,
    int Kd, short* __restrict__ Wth, short* __restrict__ Wtl)
{
    const int t = blockIdx.x * 256 + threadIdx.x;
    if (t >= 512 * 128) return;
    const int n = t >> 7, k = t & 127;
    const int mtx = n >> 7, cc = n & 127;
    const float* W = mtx == 0 ? W0 : mtx == 1 ? W1 : mtx == 2 ? W2 : W3;
    const float v = (k < Kd) ? W[(size_t)k * 128 + cc] : 0.f;
    const unsigned short hb = f2bf(v);
    Wth[t] = (short)hb;
    Wtl[t] = (short)f2bf(v - bf2f(hb));
}

// ---------------------------------------------------------------------------
// MFMA GEMM v5: R8 structure with COMPILE-TIME matrix pair (template) so the
// epilogue is branch-free per matrix, plus the exp-hoist outputs:
// pair 0 -> EK = exp(-K) fp32, EQ = exp(-Q) fp16; pair 1 -> V fp16, S fp32.
// ---------------------------------------------------------------------------
template<int PAIR>
__device__ __forceinline__ void gemm_pair(
    short (&ldsA)[2][2][64 * 64],
    const short* __restrict__ Wth, const short* __restrict__ Wtl,
    const float* __restrict__ bias0, const float* __restrict__ bias1,
    const float* __restrict__ bias2, const float* __restrict__ bias3,
    float* __restrict__ OEK, _Float16* __restrict__ OEQ,
    _Float16* __restrict__ OV, float* __restrict__ OS,
    int row0, int M, int l, int wc)
{
    const int fr = l & 15;
    const int kq = l >> 4;
    #pragma unroll
    for (int mi = 0; mi < 2; ++mi) {
        const int mtx = PAIR * 2 + mi;       // compile-time constant
        f32x4 acc[4][2] = {};
        #pragma unroll
        for (int step = 0; step < 4; ++step) {
            const int kg = step * 4 + kq;
            const int kh = kg >> 3, kk = kg & 7;
            short8v ah[4], al[4];
            #pragma unroll
            for (int m = 0; m < 4; ++m) {
                const int ar = m * 16 + fr;
                const int slot = kk ^ (ar & 7);
                ah[m] = *(const short8v*)&ldsA[0][kh][ar * 64 + slot * 8];
                al[m] = *(const short8v*)&ldsA[1][kh][ar * 64 + slot * 8];
            }
            short8v wh[2], wl[2];
            #pragma unroll
            for (int n = 0; n < 2; ++n) {
                const size_t wo = (size_t)(mtx * 128 + wc * 32 + n * 16 + fr) * 128 + kg * 8;
                wh[n] = *(const short8v*)&Wth[wo];
                wl[n] = *(const short8v*)&Wtl[wo];
            }
            #pragma unroll
            for (int m = 0; m < 4; ++m)
                #pragma unroll
                for (int n = 0; n < 2; ++n) {
                    acc[m][n] = __builtin_amdgcn_mfma_f32_16x16x32_bf16(ah[m], wh[n], acc[m][n], 0, 0, 0);
                    acc[m][n] = __builtin_amdgcn_mfma_f32_16x16x32_bf16(ah[m], wl[n], acc[m][n], 0, 0, 0);
                    acc[m][n] = __builtin_amdgcn_mfma_f32_16x16x32_bf16(al[m], wh[n], acc[m][n], 0, 0, 0);
                }
        }
        // ---- epilogue (C layout: col=lane&15, row=(lane>>4)*4+j), mtx constant
        const float* bias = (mtx == 0) ? bias0 : (mtx == 1) ? bias1
                          : (mtx == 2) ? bias2 : bias3;
        #pragma unroll
        for (int n = 0; n < 2; ++n) {
            const int col = wc * 32 + n * 16 + fr;
            const float bv = bias[col];
            #pragma unroll
            for (int m = 0; m < 4; ++m) {
                const int rb = row0 + m * 16 + kq * 4;
                #pragma unroll
                for (int j = 0; j < 4; ++j) {
                    const int r = rb + j;
                    if (r >= M) continue;
                    const float v = acc[m][n][j] + bv;
                    const size_t o = (size_t)r * 128 + col;
                    if (mtx == 0)      OEK[o] = __expf(-v);
                    else if (mtx == 1) OEQ[o] = (_Float16)__expf(-v);
                    else if (mtx == 2) OV[o]  = (_Float16)v;
                    else               OS[o]  = v;
                }
            }
        }
    }
}

__global__ __launch_bounds__(256) void gemm_mfma(
    const short* __restrict__ Ah, const short* __restrict__ Al,
    const short* __restrict__ Wth, const short* __restrict__ Wtl,
    const float* __restrict__ bias0, const float* __restrict__ bias1,
    const float* __restrict__ bias2, const float* __restrict__ bias3,
    float* __restrict__ OEK, _Float16* __restrict__ OEQ,
    _Float16* __restrict__ OV, float* __restrict__ OS, int M)
{
    __shared__ short ldsA[2][2][64 * 64];  // [hi/lo][k-half][row*64 + slot*8], 32KB
    const int t = threadIdx.x;
    const int l = t & 63, wc = t >> 6;
    const int row0 = blockIdx.x * 64;

    // ---- stage A once (R6/R8 geometry: row stride 128B, slot=(j)^(r&7), 0 conflicts)
    #pragma unroll
    for (int i = 0; i < 8; ++i) {
        const int gi = i * 256 + t;        // 0..2047
        const int tile = gi >> 10;
        const int g2 = gi & 1023;
        const int kh = g2 >> 9;
        const int r = (g2 >> 3) & 63;
        const int j = g2 & 7;
        const int slot = j ^ (r & 7);
        const short8v v = *(const short8v*)((tile ? Al : Ah)
                            + (size_t)(row0 + r) * 128 + kh * 64 + j * 8);
        *(short8v*)&ldsA[tile][kh][r * 64 + slot * 8] = v;
    }
    __syncthreads();   // the only barrier

    if (blockIdx.y == 0)
        gemm_pair<0>(ldsA, Wth, Wtl, bias0, bias1, bias2, bias3,
                     OEK, OEQ, OV, OS, row0, M, l, wc);
    else
        gemm_pair<1>(ldsA, Wth, Wtl, bias0, bias1, bias2, bias3,
                     OEK, OEQ, OV, OS, row0, M, l, wc);
}

// ---------------------------------------------------------------------------
// CSR build (unchanged)
// ---------------------------------------------------------------------------
__global__ __launch_bounds__(256) void hist_kernel(const int* __restrict__ ei,
                                                   int* __restrict__ cnt, int E)
{
    const int e = blockIdx.x * 256 + threadIdx.x;
    if (e < E) atomicAdd(&cnt[ei[E + e]], 1);
}

__global__ __launch_bounds__(256) void scan_p1(const int* __restrict__ cnt,
                                               int* __restrict__ bsum, int Nn)
{
    __shared__ int red[256];
    const int t = threadIdx.x;
    const int i = blockIdx.x * 256 + t;
    red[t] = (i < Nn) ? cnt[i] : 0;
    __syncthreads();
    for (int d = 128; d > 0; d >>= 1) {
        if (t < d) red[t] += red[t + d];
        __syncthreads();
    }
    if (t == 0) bsum[blockIdx.x] = red[0];
}

__global__ __launch_bounds__(256) void scan_p2(const int* __restrict__ bsum,
                                               int* __restrict__ bsoff,
                                               int* __restrict__ off, int Nn)
{
    __shared__ int sc[256];
    const int t = threadIdx.x;
    const int v = (t < NB_SCAN) ? bsum[t] : 0;
    sc[t] = v;
    __syncthreads();
    #pragma unroll
    for (int d = 1; d < 256; d <<= 1) {
        const int a = (t >= d) ? sc[t - d] : 0;
        __syncthreads();
        sc[t] += a;
        __syncthreads();
    }
    if (t < NB_SCAN) bsoff[t] = sc[t] - v;
    if (t == NB_SCAN - 1) off[Nn] = sc[t];
}

__global__ __launch_bounds__(256) void scan_p3(int* __restrict__ cnt,
                                               const int* __restrict__ bsoff,
                                               int* __restrict__ off, int Nn)
{
    __shared__ int sc[256];
    const int t = threadIdx.x;
    const int i = blockIdx.x * 256 + t;
    const int v = (i < Nn) ? cnt[i] : 0;
    sc[t] = v;
    __syncthreads();
    #pragma unroll
    for (int d = 1; d < 256; d <<= 1) {
        const int a = (t >= d) ? sc[t - d] : 0;
        __syncthreads();
        sc[t] += a;
        __syncthreads();
    }
    if (i < Nn) {
        const int o = bsoff[blockIdx.x] + sc[t] - v;
        off[i] = o;
        cnt[i] = o;
    }
}

__global__ __launch_bounds__(256) void scatter_kernel(const int* __restrict__ ei,
                                                      int* __restrict__ cur,
                                                      int* __restrict__ csr_src, int E)
{
    const int e = blockIdx.x * 256 + threadIdx.x;
    if (e >= E) return;
    const int s = ei[e];
    const int d = ei[E + e];
    const int pos = atomicAdd(&cur[d], 1);
    csr_src[pos] = s;
}

// ---------------------------------------------------------------------------
// CSR aggregation (unchanged from R9): gate = rcp(1 + ek*eq), fp16 gathers.
// ---------------------------------------------------------------------------
template<int FUSE>
__global__ __launch_bounds__(256) void agg_csr(
    const float* __restrict__ EKb, const _Float16* __restrict__ EQ16,
    const _Float16* __restrict__ V16, const int* __restrict__ off,
    const int* __restrict__ csr_src, float* __restrict__ hSkip,
    short* __restrict__ Ah, short* __restrict__ Al, int Nn)
{
    const int node = blockIdx.x * 4 + (threadIdx.x >> 6);
    if (node >= Nn) return;
    const int lane = threadIdx.x & 63;
    const int grp = lane >> 4;
    const int sub = lane & 15;
    const int q = sub * 8;

    const float4 kA = *(const float4*)(EKb + (size_t)node * H + q);
    const float4 kB = *(const float4*)(EKb + (size_t)node * H + q + 4);
    float acc[8] = {};

    const int begin = off[node], end = off[node + 1];
    for (int j0 = begin; j0 < end; j0 += 64) {
        const int nrem = end - j0;
        const int nk = nrem < 64 ? nrem : 64;
        const int sv = (lane < nk) ? csr_src[j0 + lane] : 0;
        #pragma unroll 2
        for (int k = 0; k < nk; k += 4) {
            const int myk = k + grp;
            const int s = __shfl(sv, myk < nk ? myk : 0);
            if (myk < nk) {
                const half8v qv = *(const half8v*)(EQ16 + (size_t)s * H + q);
                const half8v vv = *(const half8v*)(V16 + (size_t)s * H + q);
                acc[0] = fmaf((float)vv[0], __builtin_amdgcn_rcpf(fmaf(kA.x, (float)qv[0], 1.f)), acc[0]);
                acc[1] = fmaf((float)vv[1], __builtin_amdgcn_rcpf(fmaf(kA.y, (float)qv[1], 1.f)), acc[1]);
                acc[2] = fmaf((float)vv[2], __builtin_amdgcn_rcpf(fmaf(kA.z, (float)qv[2], 1.f)), acc[2]);
                acc[3] = fmaf((float)vv[3], __builtin_amdgcn_rcpf(fmaf(kA.w, (float)qv[3], 1.f)), acc[3]);
                acc[4] = fmaf((float)vv[4], __builtin_amdgcn_rcpf(fmaf(kB.x, (float)qv[4], 1.f)), acc[4]);
                acc[5] = fmaf((float)vv[5], __builtin_amdgcn_rcpf(fmaf(kB.y, (float)qv[5], 1.f)), acc[5]);
                acc[6] = fmaf((float)vv[6], __builtin_amdgcn_rcpf(fmaf(kB.z, (float)qv[6], 1.f)), acc[6]);
                acc[7] = fmaf((float)vv[7], __builtin_amdgcn_rcpf(fmaf(kB.w, (float)qv[7], 1.f)), acc[7]);
            }
        }
    }
    #pragma unroll
    for (int i = 0; i < 8; ++i) {
        acc[i] += __shfl_xor(acc[i], 16);
        acc[i] += __shfl_xor(acc[i], 32);
    }
    if (grp == 0) {
        const float* sk = hSkip + (size_t)node * H + q;
        const float4 eA = *(const float4*)sk;
        const float4 eB = *(const float4*)(sk + 4);
        float h[8];
        h[0] = eA.x + acc[0]; h[1] = eA.y + acc[1];
        h[2] = eA.z + acc[2]; h[3] = eA.w + acc[3];
        h[4] = eB.x + acc[4]; h[5] = eB.y + acc[5];
        h[6] = eB.z + acc[6]; h[7] = eB.w + acc[7];
        if (FUSE) {
            short8v hv, lv;
            #pragma unroll
            for (int j = 0; j < 8; ++j) {
                const float v = fmaxf(h[j], 0.f);
                const unsigned short hb = f2bf(v);
                hv[j] = (short)hb;
                lv[j] = (short)f2bf(v - bf2f(hb));
            }
            const size_t o = (size_t)node * 128 + q;
            *(short8v*)&Ah[o] = hv;
            *(short8v*)&Al[o] = lv;
        } else {
            float* o = hSkip + (size_t)node * H + q;
            *(float4*)o = make_float4(h[0], h[1], h[2], h[3]);
            *(float4*)(o + 4) = make_float4(h[4], h[5], h[6], h[7]);
        }
    }
}

// ---------------------------------------------------------------------------
// Pool + MLP (unchanged)
// ---------------------------------------------------------------------------
__global__ __launch_bounds__(256) void gstart_kernel(const int* __restrict__ batch,
                                                     int* __restrict__ gstart, int Nn)
{
    const int n = blockIdx.x * 256 + threadIdx.x;
    if (n >= Nn) return;
    const int b = batch[n];
    const int bp = (n == 0) ? -1 : batch[n - 1];
    for (int g = bp + 1; g <= b; ++g) gstart[g] = n;
    if (n == Nn - 1)
        for (int g = b + 1; g <= N_GRAPHS; ++g) gstart[g] = Nn;
}

__global__ __launch_bounds__(128) void pool_seg(const float* __restrict__ h,
                                                const int* __restrict__ gstart,
                                                float* __restrict__ hg)
{
    const int g = blockIdx.x;
    const int part = blockIdx.y;
    const int t = threadIdx.x;
    const int b0 = gstart[g], b1 = gstart[g + 1];
    float acc = 0.f;
    for (int n = b0 + part; n < b1; n += 4) acc += h[(size_t)n * H + t];
    atomicAdd(&hg[(size_t)g * H + t], acc);
}

__global__ __launch_bounds__(64) void mlp_kernel(
    const float* __restrict__ hg,
    const float* __restrict__ W4, const float* __restrict__ b4,
    const float* __restrict__ W5, const float* __restrict__ b5,
    float* __restrict__ out)
{
    const int g = blockIdx.x;
    const int c = threadIdx.x;
    __shared__ float hrow[H];
    for (int k = c; k < H; k += 64) hrow[k] = hg[(size_t)g * H + k];
    __syncthreads();
    float s = b4[c];
    #pragma unroll 8
    for (int k = 0; k < H; ++k) s += hrow[k] * W4[(size_t)k * 64 + c];
    s = fmaxf(s, 0.f) * W5[c];
    #pragma unroll
    for (int off = 32; off > 0; off >>= 1) s += __shfl_down(s, off);
    if (c == 0) out[g] = 1.f / (1.f + __expf(-(s + b5[0])));
}

// ---------------------------------------------------------------------------
extern "C" void kernel_launch(void* const* d_in, const int* in_sizes, int n_in,
                              void* d_out, int out_size, void* d_ws, size_t ws_size,
                              hipStream_t stream)
{
    const float* x = (const float*)d_in[0];
    const float *Wk[3], *bk[3], *Wq[3], *bq[3], *Wv[3], *bv[3], *Wsk[3], *bs[3];
    for (int l = 0; l < 3; ++l) {
        const int base = 2 + l * 8;
        Wk[l]  = (const float*)d_in[base + 0]; bk[l] = (const float*)d_in[base + 1];
        Wq[l]  = (const float*)d_in[base + 2]; bq[l] = (const float*)d_in[base + 3];
        Wv[l]  = (const float*)d_in[base + 4]; bv[l] = (const float*)d_in[base + 5];
        Wsk[l] = (const float*)d_in[base + 6]; bs[l] = (const float*)d_in[base + 7];
    }
    const float* W4 = (const float*)d_in[26];
    const float* b4 = (const float*)d_in[27];
    const float* W5 = (const float*)d_in[28];
    const float* b5 = (const float*)d_in[29];
    const int* ei    = (const int*)d_in[30];
    const int* batch = (const int*)d_in[31];
    float* out = (float*)d_out;

    const size_t NH = (size_t)N_NODES * H;
    const size_t AH = (size_t)MP * 128;
    const size_t WH = (size_t)3 * 512 * 128;
    float*     EKb  = (float*)d_ws;
    float*     hbuf = EKb + NH;
    _Float16*  EQ16 = (_Float16*)(hbuf + NH);
    _Float16*  V16  = EQ16 + NH;
    short*     Ahb  = (short*)(V16 + NH);
    short*     Alb  = Ahb + AH;
    short*     Wth  = Alb + AH;
    short*     Wtl  = Wth + WH;
    float*     hg   = (float*)(Wtl + WH);                 // G*H (zeroed)
    int*       off  = (int*)(hg + (size_t)N_GRAPHS * H);  // N+1 (zeroed)
    int*       cnt  = off + (N_NODES + 1);                // N   (zeroed)
    int*       csr  = cnt + N_NODES;                      // E
    int*       gst  = csr + N_EDGES;                      // G+1
    int*       bsum = gst + (N_GRAPHS + 1);               // 256
    int*       bsoff= bsum + 256;                         // 256
    const size_t need = (2 * NH + (size_t)N_GRAPHS * H) * sizeof(float)
                      + 2 * NH * sizeof(_Float16)
                      + (2 * AH + 2 * WH) * sizeof(short)
                      + (size_t)(2 * N_NODES + 1 + N_EDGES + N_GRAPHS + 1 + 512) * sizeof(int);
    if (ws_size < need) return;

    const int eblk = (N_EDGES + 255) / 256;
    const int ablk = (N_NODES + 3) / 4;
    const int nblk = (N_NODES + 255) / 256;
    const int cablk = (MP * 16) / 256;
    const dim3 ggrid(MP / 64, 2);        // 782 x 2 = 1564 blocks
    const dim3 pgrid(N_GRAPHS, 4);

    // ---- one fused memset: hg (pool accum) + off + cnt (contiguous)
    hipMemsetAsync(hg, 0,
        ((size_t)N_GRAPHS * H + 2 * N_NODES + 1) * sizeof(int), stream);

    // ---- CSR + graph segments + weight conversion (reused across layers)
    hist_kernel<<<eblk, 256, 0, stream>>>(ei, cnt, N_EDGES);
    scan_p1<<<NB_SCAN, 256, 0, stream>>>(cnt, bsum, N_NODES);
    scan_p2<<<1, 256, 0, stream>>>(bsum, bsoff, off, N_NODES);
    scan_p3<<<NB_SCAN, 256, 0, stream>>>(cnt, bsoff, off, N_NODES);
    scatter_kernel<<<eblk, 256, 0, stream>>>(ei, cnt, csr, N_EDGES);
    gstart_kernel<<<nblk, 256, 0, stream>>>(batch, gst, N_NODES);
    conv_W<<<256, 256, 0, stream>>>(Wk[0], Wq[0], Wv[0], Wsk[0], DIN, Wth,               Wtl);
    conv_W<<<256, 256, 0, stream>>>(Wk[1], Wq[1], Wv[1], Wsk[1], H,   Wth + 512 * 128,  Wtl + 512 * 128);
    conv_W<<<256, 256, 0, stream>>>(Wk[2], Wq[2], Wv[2], Wsk[2], H,   Wth + 1024 * 128, Wtl + 1024 * 128);

    // ---- Layer 1 (conv_A writes all MP rows incl. zero pads, reused by L2/L3)
    conv_A<<<cablk, 256, 0, stream>>>(x, N_NODES, DIN, Ahb, Alb);
    gemm_mfma<<<ggrid, 256, 0, stream>>>(Ahb, Alb, Wth, Wtl,
        bk[0], bq[0], bv[0], bs[0], EKb, EQ16, V16, hbuf, N_NODES);
    agg_csr<1><<<ablk, 256, 0, stream>>>(EKb, EQ16, V16, off, csr, hbuf, Ahb, Alb, N_NODES);

    // ---- Layer 2
    gemm_mfma<<<ggrid, 256, 0, stream>>>(Ahb, Alb, Wth + 512 * 128, Wtl + 512 * 128,
        bk[1], bq[1], bv[1], bs[1], EKb, EQ16, V16, hbuf, N_NODES);
    agg_csr<1><<<ablk, 256, 0, stream>>>(EKb, EQ16, V16, off, csr, hbuf, Ahb, Alb, N_NODES);

    // ---- Layer 3
    gemm_mfma<<<ggrid, 256, 0, stream>>>(Ahb, Alb, Wth + 1024 * 128, Wtl + 1024 * 128,
        bk[2], bq[2], bv[2], bs[2], EKb, EQ16, V16, hbuf, N_NODES);
    agg_csr<0><<<ablk, 256, 0, stream>>>(EKb, EQ16, V16, off, csr, hbuf, Ahb, Alb, N_NODES);

    // ---- Pool + MLP
    pool_seg<<<pgrid, 128, 0, stream>>>(hbuf, gst, hg);
    mlp_kernel<<<N_GRAPHS, 64, 0, stream>>>(hg, W4, b4, W5, b5, out);
}

// Round 11
// 484.279 us; speedup vs baseline: 1.0861x; 1.0861x over previous
//
#include <hip/hip_runtime.h>

#define N_NODES 50000
#define N_EDGES 800000
#define N_GRAPHS 256
#define DIN 126
#define H 128
#define MP 50048           // N_NODES padded to 128
#define NB_SCAN 196        // ceil(N_NODES/256)

typedef __attribute__((ext_vector_type(8))) short short8v;
typedef __attribute__((ext_vector_type(8))) _Float16 half8v;
typedef __attribute__((ext_vector_type(4))) float f32x4;

// ---------------------------------------------------------------------------
// fp32 -> bf16 hi/lo split helpers (RNE)
// ---------------------------------------------------------------------------
__device__ __forceinline__ unsigned short f2bf(float f) {
    const unsigned u = __float_as_uint(f);
    return (unsigned short)((u + 0x7FFFu + ((u >> 16) & 1u)) >> 16);
}
__device__ __forceinline__ float bf2f(unsigned short s) {
    return __uint_as_float(((unsigned)s) << 16);
}

// ---------------------------------------------------------------------------
// A conversion (layer-1 input only): X fp32 [M,Kd] -> Ah,Al bf16 [MP][128]
// ---------------------------------------------------------------------------
__global__ __launch_bounds__(256) void conv_A(const float* __restrict__ X, int M, int Kd,
                                              short* __restrict__ Ah,
                                              short* __restrict__ Al)
{
    const int t = blockIdx.x * 256 + threadIdx.x;
    const int row = t >> 4;
    if (row >= MP) return;
    const int k0 = (t & 15) * 8;
    short8v hv, lv;
    #pragma unroll
    for (int j = 0; j < 8; ++j) {
        const int k = k0 + j;
        float v = 0.f;
        if (row < M && k < Kd) v = X[(size_t)row * Kd + k];
        const unsigned short hb = f2bf(v);
        const float lo = v - bf2f(hb);
        hv[j] = (short)hb;
        lv[j] = (short)f2bf(lo);
    }
    const size_t o = (size_t)row * 128 + k0;
    *(short8v*)&Ah[o] = hv;
    *(short8v*)&Al[o] = lv;
}

// ---------------------------------------------------------------------------
// W conversion, all 3 layers in one launch: 12 x [Kd,128] fp32 ->
// transposed Wth/Wtl bf16 [3][512 n][128 k], zero-padded past Kd.
// ---------------------------------------------------------------------------
struct WPtrs { const float* w[12]; };

__global__ __launch_bounds__(256) void conv_W3(WPtrs P, short* __restrict__ Wth,
                                               short* __restrict__ Wtl)
{
    const int t = blockIdx.x * 256 + threadIdx.x;
    if (t >= 3 * 512 * 128) return;
    const int layer = t >> 16;            // 65536 elems per layer
    const int r = t & 65535;
    const int n = r >> 7, k = r & 127;
    const int mtx = n >> 7, cc = n & 127;
    const int Kd = (layer == 0) ? DIN : H;
    const float* W = P.w[layer * 4 + mtx];
    const float v = (k < Kd) ? W[(size_t)k * 128 + cc] : 0.f;
    const unsigned short hb = f2bf(v);
    Wth[t] = (short)hb;
    Wtl[t] = (short)f2bf(v - bf2f(hb));
}

// ---------------------------------------------------------------------------
// MFMA GEMM v6: R8 structure + exp-hoist outputs.  Block = 64 A-rows x 2
// weight matrices (blockIdx.y picks the pair).  A staged once in 32KB LDS
// (row stride 128B, slot=(k&7)^(r&7): 0 bank conflicts, R8-verified).
// W from global (L2-hot).  Epilogue: runtime-mtx branch hoisted OUTSIDE the
// store nests (R8 codegen shape; the R9 inner-loop branch cost +20us, the
// R10 template pair cost +40 VGPR).  launch_bounds(256,5) pins VGPR<=102
// so occupancy stays LDS-limited at 5 blocks/CU.
// Outputs: EK=exp(-K) fp32, EQ=exp(-Q) fp16, V fp16, S fp32.
// ---------------------------------------------------------------------------
__global__ __launch_bounds__(256, 5) void gemm_mfma(
    const short* __restrict__ Ah, const short* __restrict__ Al,
    const short* __restrict__ Wth, const short* __restrict__ Wtl,
    const float* __restrict__ bias0, const float* __restrict__ bias1,
    const float* __restrict__ bias2, const float* __restrict__ bias3,
    float* __restrict__ OEK, _Float16* __restrict__ OEQ,
    _Float16* __restrict__ OV, float* __restrict__ OS, int M)
{
    __shared__ short ldsA[2][2][64 * 64];  // [hi/lo][k-half][row*64 + slot*8], 32KB
    const int t = threadIdx.x;
    const int l = t & 63, wc = t >> 6;
    const int row0 = blockIdx.x * 64;
    const int mp = blockIdx.y;             // matrix pair: {0,1} or {2,3}
    const int fr = l & 15;
    const int kq = l >> 4;

    #pragma unroll
    for (int i = 0; i < 8; ++i) {
        const int gi = i * 256 + t;        // 0..2047
        const int tile = gi >> 10;
        const int g2 = gi & 1023;
        const int kh = g2 >> 9;
        const int r = (g2 >> 3) & 63;
        const int j = g2 & 7;
        const int slot = j ^ (r & 7);
        const short8v v = *(const short8v*)((tile ? Al : Ah)
                            + (size_t)(row0 + r) * 128 + kh * 64 + j * 8);
        *(short8v*)&ldsA[tile][kh][r * 64 + slot * 8] = v;
    }
    __syncthreads();   // the only barrier

    #pragma unroll
    for (int mi = 0; mi < 2; ++mi) {
        const int mtx = mp * 2 + mi;
        f32x4 acc[4][2] = {};
        #pragma unroll
        for (int step = 0; step < 4; ++step) {
            const int kg = step * 4 + kq;
            const int kh = kg >> 3, kk = kg & 7;
            short8v ah[4], al[4];
            #pragma unroll
            for (int m = 0; m < 4; ++m) {
                const int ar = m * 16 + fr;
                const int slot = kk ^ (ar & 7);
                ah[m] = *(const short8v*)&ldsA[0][kh][ar * 64 + slot * 8];
                al[m] = *(const short8v*)&ldsA[1][kh][ar * 64 + slot * 8];
            }
            short8v wh[2], wl[2];
            #pragma unroll
            for (int n = 0; n < 2; ++n) {
                const size_t wo = (size_t)(mtx * 128 + wc * 32 + n * 16 + fr) * 128 + kg * 8;
                wh[n] = *(const short8v*)&Wth[wo];
                wl[n] = *(const short8v*)&Wtl[wo];
            }
            #pragma unroll
            for (int m = 0; m < 4; ++m)
                #pragma unroll
                for (int n = 0; n < 2; ++n) {
                    acc[m][n] = __builtin_amdgcn_mfma_f32_16x16x32_bf16(ah[m], wh[n], acc[m][n], 0, 0, 0);
                    acc[m][n] = __builtin_amdgcn_mfma_f32_16x16x32_bf16(ah[m], wl[n], acc[m][n], 0, 0, 0);
                    acc[m][n] = __builtin_amdgcn_mfma_f32_16x16x32_bf16(al[m], wh[n], acc[m][n], 0, 0, 0);
                }
        }
        // ---- epilogue: branch hoisted outside the store nests (R8 shape)
        const float* bias = (mtx == 0) ? bias0 : (mtx == 1) ? bias1
                          : (mtx == 2) ? bias2 : bias3;
        if (mtx == 0) {
            #pragma unroll
            for (int n = 0; n < 2; ++n) {
                const int col = wc * 32 + n * 16 + fr;
                const float bv = bias[col];
                #pragma unroll
                for (int m = 0; m < 4; ++m) {
                    const int rb = row0 + m * 16 + kq * 4;
                    #pragma unroll
                    for (int j = 0; j < 4; ++j) {
                        const int r = rb + j;
                        if (r < M) OEK[(size_t)r * 128 + col] = __expf(-(acc[m][n][j] + bv));
                    }
                }
            }
        } else if (mtx == 1) {
            #pragma unroll
            for (int n = 0; n < 2; ++n) {
                const int col = wc * 32 + n * 16 + fr;
                const float bv = bias[col];
                #pragma unroll
                for (int m = 0; m < 4; ++m) {
                    const int rb = row0 + m * 16 + kq * 4;
                    #pragma unroll
                    for (int j = 0; j < 4; ++j) {
                        const int r = rb + j;
                        if (r < M) OEQ[(size_t)r * 128 + col] = (_Float16)__expf(-(acc[m][n][j] + bv));
                    }
                }
            }
        } else if (mtx == 2) {
            #pragma unroll
            for (int n = 0; n < 2; ++n) {
                const int col = wc * 32 + n * 16 + fr;
                const float bv = bias[col];
                #pragma unroll
                for (int m = 0; m < 4; ++m) {
                    const int rb = row0 + m * 16 + kq * 4;
                    #pragma unroll
                    for (int j = 0; j < 4; ++j) {
                        const int r = rb + j;
                        if (r < M) OV[(size_t)r * 128 + col] = (_Float16)(acc[m][n][j] + bv);
                    }
                }
            }
        } else {
            #pragma unroll
            for (int n = 0; n < 2; ++n) {
                const int col = wc * 32 + n * 16 + fr;
                const float bv = bias[col];
                #pragma unroll
                for (int m = 0; m < 4; ++m) {
                    const int rb = row0 + m * 16 + kq * 4;
                    #pragma unroll
                    for (int j = 0; j < 4; ++j) {
                        const int r = rb + j;
                        if (r < M) OS[(size_t)r * 128 + col] = acc[m][n][j] + bv;
                    }
                }
            }
        }
    }
}

// ---------------------------------------------------------------------------
// CSR build (unchanged)
// ---------------------------------------------------------------------------
__global__ __launch_bounds__(256) void hist_kernel(const int* __restrict__ ei,
                                                   int* __restrict__ cnt, int E)
{
    const int e = blockIdx.x * 256 + threadIdx.x;
    if (e < E) atomicAdd(&cnt[ei[E + e]], 1);
}

__global__ __launch_bounds__(256) void scan_p1(const int* __restrict__ cnt,
                                               int* __restrict__ bsum, int Nn)
{
    __shared__ int red[256];
    const int t = threadIdx.x;
    const int i = blockIdx.x * 256 + t;
    red[t] = (i < Nn) ? cnt[i] : 0;
    __syncthreads();
    for (int d = 128; d > 0; d >>= 1) {
        if (t < d) red[t] += red[t + d];
        __syncthreads();
    }
    if (t == 0) bsum[blockIdx.x] = red[0];
}

__global__ __launch_bounds__(256) void scan_p2(const int* __restrict__ bsum,
                                               int* __restrict__ bsoff,
                                               int* __restrict__ off, int Nn)
{
    __shared__ int sc[256];
    const int t = threadIdx.x;
    const int v = (t < NB_SCAN) ? bsum[t] : 0;
    sc[t] = v;
    __syncthreads();
    #pragma unroll
    for (int d = 1; d < 256; d <<= 1) {
        const int a = (t >= d) ? sc[t - d] : 0;
        __syncthreads();
        sc[t] += a;
        __syncthreads();
    }
    if (t < NB_SCAN) bsoff[t] = sc[t] - v;
    if (t == NB_SCAN - 1) off[Nn] = sc[t];
}

__global__ __launch_bounds__(256) void scan_p3(int* __restrict__ cnt,
                                               const int* __restrict__ bsoff,
                                               int* __restrict__ off, int Nn)
{
    __shared__ int sc[256];
    const int t = threadIdx.x;
    const int i = blockIdx.x * 256 + t;
    const int v = (i < Nn) ? cnt[i] : 0;
    sc[t] = v;
    __syncthreads();
    #pragma unroll
    for (int d = 1; d < 256; d <<= 1) {
        const int a = (t >= d) ? sc[t - d] : 0;
        __syncthreads();
        sc[t] += a;
        __syncthreads();
    }
    if (i < Nn) {
        const int o = bsoff[blockIdx.x] + sc[t] - v;
        off[i] = o;
        cnt[i] = o;
    }
}

__global__ __launch_bounds__(256) void scatter_kernel(const int* __restrict__ ei,
                                                      int* __restrict__ cur,
                                                      int* __restrict__ csr_src, int E)
{
    const int e = blockIdx.x * 256 + threadIdx.x;
    if (e >= E) return;
    const int s = ei[e];
    const int d = ei[E + e];
    const int pos = atomicAdd(&cur[d], 1);
    csr_src[pos] = s;
}

// ---------------------------------------------------------------------------
// CSR aggregation (unchanged from R9): gate = rcp(1 + ek*eq), fp16 gathers.
// ---------------------------------------------------------------------------
template<int FUSE>
__global__ __launch_bounds__(256) void agg_csr(
    const float* __restrict__ EKb, const _Float16* __restrict__ EQ16,
    const _Float16* __restrict__ V16, const int* __restrict__ off,
    const int* __restrict__ csr_src, float* __restrict__ hSkip,
    short* __restrict__ Ah, short* __restrict__ Al, int Nn)
{
    const int node = blockIdx.x * 4 + (threadIdx.x >> 6);
    if (node >= Nn) return;
    const int lane = threadIdx.x & 63;
    const int grp = lane >> 4;
    const int sub = lane & 15;
    const int q = sub * 8;

    const float4 kA = *(const float4*)(EKb + (size_t)node * H + q);
    const float4 kB = *(const float4*)(EKb + (size_t)node * H + q + 4);
    float acc[8] = {};

    const int begin = off[node], end = off[node + 1];
    for (int j0 = begin; j0 < end; j0 += 64) {
        const int nrem = end - j0;
        const int nk = nrem < 64 ? nrem : 64;
        const int sv = (lane < nk) ? csr_src[j0 + lane] : 0;
        #pragma unroll 2
        for (int k = 0; k < nk; k += 4) {
            const int myk = k + grp;
            const int s = __shfl(sv, myk < nk ? myk : 0);
            if (myk < nk) {
                const half8v qv = *(const half8v*)(EQ16 + (size_t)s * H + q);
                const half8v vv = *(const half8v*)(V16 + (size_t)s * H + q);
                acc[0] = fmaf((float)vv[0], __builtin_amdgcn_rcpf(fmaf(kA.x, (float)qv[0], 1.f)), acc[0]);
                acc[1] = fmaf((float)vv[1], __builtin_amdgcn_rcpf(fmaf(kA.y, (float)qv[1], 1.f)), acc[1]);
                acc[2] = fmaf((float)vv[2], __builtin_amdgcn_rcpf(fmaf(kA.z, (float)qv[2], 1.f)), acc[2]);
                acc[3] = fmaf((float)vv[3], __builtin_amdgcn_rcpf(fmaf(kA.w, (float)qv[3], 1.f)), acc[3]);
                acc[4] = fmaf((float)vv[4], __builtin_amdgcn_rcpf(fmaf(kB.x, (float)qv[4], 1.f)), acc[4]);
                acc[5] = fmaf((float)vv[5], __builtin_amdgcn_rcpf(fmaf(kB.y, (float)qv[5], 1.f)), acc[5]);
                acc[6] = fmaf((float)vv[6], __builtin_amdgcn_rcpf(fmaf(kB.z, (float)qv[6], 1.f)), acc[6]);
                acc[7] = fmaf((float)vv[7], __builtin_amdgcn_rcpf(fmaf(kB.w, (float)qv[7], 1.f)), acc[7]);
            }
        }
    }
    #pragma unroll
    for (int i = 0; i < 8; ++i) {
        acc[i] += __shfl_xor(acc[i], 16);
        acc[i] += __shfl_xor(acc[i], 32);
    }
    if (grp == 0) {
        const float* sk = hSkip + (size_t)node * H + q;
        const float4 eA = *(const float4*)sk;
        const float4 eB = *(const float4*)(sk + 4);
        float h[8];
        h[0] = eA.x + acc[0]; h[1] = eA.y + acc[1];
        h[2] = eA.z + acc[2]; h[3] = eA.w + acc[3];
        h[4] = eB.x + acc[4]; h[5] = eB.y + acc[5];
        h[6] = eB.z + acc[6]; h[7] = eB.w + acc[7];
        if (FUSE) {
            short8v hv, lv;
            #pragma unroll
            for (int j = 0; j < 8; ++j) {
                const float v = fmaxf(h[j], 0.f);
                const unsigned short hb = f2bf(v);
                hv[j] = (short)hb;
                lv[j] = (short)f2bf(v - bf2f(hb));
            }
            const size_t o = (size_t)node * 128 + q;
            *(short8v*)&Ah[o] = hv;
            *(short8v*)&Al[o] = lv;
        } else {
            float* o = hSkip + (size_t)node * H + q;
            *(float4*)o = make_float4(h[0], h[1], h[2], h[3]);
            *(float4*)(o + 4) = make_float4(h[4], h[5], h[6], h[7]);
        }
    }
}

// ---------------------------------------------------------------------------
// Pool + MLP (unchanged)
// ---------------------------------------------------------------------------
__global__ __launch_bounds__(256) void gstart_kernel(const int* __restrict__ batch,
                                                     int* __restrict__ gstart, int Nn)
{
    const int n = blockIdx.x * 256 + threadIdx.x;
    if (n >= Nn) return;
    const int b = batch[n];
    const int bp = (n == 0) ? -1 : batch[n - 1];
    for (int g = bp + 1; g <= b; ++g) gstart[g] = n;
    if (n == Nn - 1)
        for (int g = b + 1; g <= N_GRAPHS; ++g) gstart[g] = Nn;
}

__global__ __launch_bounds__(128) void pool_seg(const float* __restrict__ h,
                                                const int* __restrict__ gstart,
                                                float* __restrict__ hg)
{
    const int g = blockIdx.x;
    const int part = blockIdx.y;
    const int t = threadIdx.x;
    const int b0 = gstart[g], b1 = gstart[g + 1];
    float acc = 0.f;
    for (int n = b0 + part; n < b1; n += 4) acc += h[(size_t)n * H + t];
    atomicAdd(&hg[(size_t)g * H + t], acc);
}

__global__ __launch_bounds__(64) void mlp_kernel(
    const float* __restrict__ hg,
    const float* __restrict__ W4, const float* __restrict__ b4,
    const float* __restrict__ W5, const float* __restrict__ b5,
    float* __restrict__ out)
{
    const int g = blockIdx.x;
    const int c = threadIdx.x;
    __shared__ float hrow[H];
    for (int k = c; k < H; k += 64) hrow[k] = hg[(size_t)g * H + k];
    __syncthreads();
    float s = b4[c];
    #pragma unroll 8
    for (int k = 0; k < H; ++k) s += hrow[k] * W4[(size_t)k * 64 + c];
    s = fmaxf(s, 0.f) * W5[c];
    #pragma unroll
    for (int off = 32; off > 0; off >>= 1) s += __shfl_down(s, off);
    if (c == 0) out[g] = 1.f / (1.f + __expf(-(s + b5[0])));
}

// ---------------------------------------------------------------------------
extern "C" void kernel_launch(void* const* d_in, const int* in_sizes, int n_in,
                              void* d_out, int out_size, void* d_ws, size_t ws_size,
                              hipStream_t stream)
{
    const float* x = (const float*)d_in[0];
    const float *Wk[3], *bk[3], *Wq[3], *bq[3], *Wv[3], *bv[3], *Wsk[3], *bs[3];
    for (int l = 0; l < 3; ++l) {
        const int base = 2 + l * 8;
        Wk[l]  = (const float*)d_in[base + 0]; bk[l] = (const float*)d_in[base + 1];
        Wq[l]  = (const float*)d_in[base + 2]; bq[l] = (const float*)d_in[base + 3];
        Wv[l]  = (const float*)d_in[base + 4]; bv[l] = (const float*)d_in[base + 5];
        Wsk[l] = (const float*)d_in[base + 6]; bs[l] = (const float*)d_in[base + 7];
    }
    const float* W4 = (const float*)d_in[26];
    const float* b4 = (const float*)d_in[27];
    const float* W5 = (const float*)d_in[28];
    const float* b5 = (const float*)d_in[29];
    const int* ei    = (const int*)d_in[30];
    const int* batch = (const int*)d_in[31];
    float* out = (float*)d_out;

    const size_t NH = (size_t)N_NODES * H;
    const size_t AH = (size_t)MP * 128;
    const size_t WH = (size_t)3 * 512 * 128;
    float*     EKb  = (float*)d_ws;
    float*     hbuf = EKb + NH;
    _Float16*  EQ16 = (_Float16*)(hbuf + NH);
    _Float16*  V16  = EQ16 + NH;
    short*     Ahb  = (short*)(V16 + NH);
    short*     Alb  = Ahb + AH;
    short*     Wth  = Alb + AH;
    short*     Wtl  = Wth + WH;
    float*     hg   = (float*)(Wtl + WH);                 // G*H (zeroed)
    int*       off  = (int*)(hg + (size_t)N_GRAPHS * H);  // N+1 (zeroed)
    int*       cnt  = off + (N_NODES + 1);                // N   (zeroed)
    int*       csr  = cnt + N_NODES;                      // E
    int*       gst  = csr + N_EDGES;                      // G+1
    int*       bsum = gst + (N_GRAPHS + 1);               // 256
    int*       bsoff= bsum + 256;                         // 256
    const size_t need = (2 * NH + (size_t)N_GRAPHS * H) * sizeof(float)
                      + 2 * NH * sizeof(_Float16)
                      + (2 * AH + 2 * WH) * sizeof(short)
                      + (size_t)(2 * N_NODES + 1 + N_EDGES + N_GRAPHS + 1 + 512) * sizeof(int);
    if (ws_size < need) return;

    const int eblk = (N_EDGES + 255) / 256;
    const int ablk = (N_NODES + 3) / 4;
    const int nblk = (N_NODES + 255) / 256;
    const int cablk = (MP * 16) / 256;
    const dim3 ggrid(MP / 64, 2);        // 782 x 2 = 1564 blocks
    const dim3 pgrid(N_GRAPHS, 4);

    // ---- one fused memset: hg (pool accum) + off + cnt (contiguous)
    hipMemsetAsync(hg, 0,
        ((size_t)N_GRAPHS * H + 2 * N_NODES + 1) * sizeof(int), stream);

    // ---- CSR + graph segments + weight conversion (reused across layers)
    hist_kernel<<<eblk, 256, 0, stream>>>(ei, cnt, N_EDGES);
    scan_p1<<<NB_SCAN, 256, 0, stream>>>(cnt, bsum, N_NODES);
    scan_p2<<<1, 256, 0, stream>>>(bsum, bsoff, off, N_NODES);
    scan_p3<<<NB_SCAN, 256, 0, stream>>>(cnt, bsoff, off, N_NODES);
    scatter_kernel<<<eblk, 256, 0, stream>>>(ei, cnt, csr, N_EDGES);
    gstart_kernel<<<nblk, 256, 0, stream>>>(batch, gst, N_NODES);
    WPtrs wp;
    for (int l = 0; l < 3; ++l) {
        wp.w[l * 4 + 0] = Wk[l];
        wp.w[l * 4 + 1] = Wq[l];
        wp.w[l * 4 + 2] = Wv[l];
        wp.w[l * 4 + 3] = Wsk[l];
    }
    conv_W3<<<768, 256, 0, stream>>>(wp, Wth, Wtl);

    // ---- Layer 1 (conv_A writes all MP rows incl. zero pads, reused by L2/L3)
    conv_A<<<cablk, 256, 0, stream>>>(x, N_NODES, DIN, Ahb, Alb);
    gemm_mfma<<<ggrid, 256, 0, stream>>>(Ahb, Alb, Wth, Wtl,
        bk[0], bq[0], bv[0], bs[0], EKb, EQ16, V16, hbuf, N_NODES);
    agg_csr<1><<<ablk, 256, 0, stream>>>(EKb, EQ16, V16, off, csr, hbuf, Ahb, Alb, N_NODES);

    // ---- Layer 2
    gemm_mfma<<<ggrid, 256, 0, stream>>>(Ahb, Alb, Wth + 512 * 128, Wtl + 512 * 128,
        bk[1], bq[1], bv[1], bs[1], EKb, EQ16, V16, hbuf, N_NODES);
    agg_csr<1><<<ablk, 256, 0, stream>>>(EKb, EQ16, V16, off, csr, hbuf, Ahb, Alb, N_NODES);

    // ---- Layer 3
    gemm_mfma<<<ggrid, 256, 0, stream>>>(Ahb, Alb, Wth + 1024 * 128, Wtl + 1024 * 128,
        bk[2], bq[2], bv[2], bs[2], EKb, EQ16, V16, hbuf, N_NODES);
    agg_csr<0><<<ablk, 256, 0, stream>>>(EKb, EQ16, V16, off, csr, hbuf, Ahb, Alb, N_NODES);

    // ---- Pool + MLP
    pool_seg<<<pgrid, 128, 0, stream>>>(hbuf, gst, hg);
    mlp_kernel<<<N_GRAPHS, 64, 0, stream>>>(hg, W4, b4, W5, b5, out);
}